// Round 1
// baseline (1016.235 us; speedup 1.0000x reference)
//
#include <hip/hip_runtime.h>

// Fused windowed masked attention, one workgroup per (b,p,h) slice.
// B=2,P=64,H=8 -> 1024 slices; I=J=256, D=64. fp32 in/out, bf16 MFMA inside.
//
// v2: 512-thread workgroups (8 waves x 2 i-chunks, was 4 waves x 4 chunks).
// LDS stays 64 KiB -> still 2 WG/CU, but now 16 waves/CU resident (was 8),
// doubling memory-level parallelism for the pos/mask stream (latency-bound).
//
// Layout notes (gfx950 mfma_f32_16x16x32_bf16, all HW-verified mappings):
//   A-frag: A[m=lane&15][k=(lane>>4)*8+jj], jj=0..7
//   B-frag: B[k=(lane>>4)*8+jj][n=lane&15]
//   C/D   : col=lane&15, row=(lane>>4)*4+reg
// We compute simT = K*Q^T (rows=j, cols=i) so softmax-over-j reduces in-lane
// (4 regs x 16 tiles) plus shfl_xor(16),shfl_xor(32).

typedef short short8 __attribute__((ext_vector_type(8)));
typedef float f32x4 __attribute__((ext_vector_type(4)));
typedef int int4v __attribute__((ext_vector_type(4)));

__device__ __forceinline__ unsigned bf16r(float x) {
  unsigned u = __float_as_uint(x);
  return (u + 0x7FFFu + ((u >> 16) & 1u)) >> 16;  // round-to-nearest-even
}
__device__ __forceinline__ unsigned pk(float a, float b) {
  return bf16r(a) | (bf16r(b) << 16);
}
__device__ __forceinline__ short8 pack8(float4 a, float4 b) {
  int4v t;
  t[0] = (int)pk(a.x, a.y); t[1] = (int)pk(a.z, a.w);
  t[2] = (int)pk(b.x, b.y); t[3] = (int)pk(b.z, b.w);
  return __builtin_bit_cast(short8, t);
}

__global__ __launch_bounds__(512, 4)
void WindowedMaskedAttentionCalculation_72189810311255_kernel(
    const float* __restrict__ q, const float* __restrict__ k,
    const float* __restrict__ v, const float* __restrict__ pos,
    const float* __restrict__ msk, float* __restrict__ out) {
  // K bf16 row-major [256][64], 128B rows; 16B granule swizzled by (j&7).
  // Vt bf16 [64][256] (V transposed), 512B rows; granule swizzled by (d&15).
  __shared__ unsigned short Kb[16384];   // 32 KiB
  __shared__ unsigned short Vt[16384];   // 32 KiB  -> 64 KiB total, 2 WG/CU

  const int s = blockIdx.x;
  const int tid = threadIdx.x;
  const size_t qkvOff = (size_t)s * 16384;   // 256*64
  const size_t pmOff = (size_t)s * 65536;    // 256*256

  // ---------------- stage K (swizzled) and V^T (swizzled) ----------------
  const float4* K4 = (const float4*)(k + qkvOff);
  const float4* V4 = (const float4*)(v + qkvOff);
#pragma unroll
  for (int it = 0; it < 8; ++it) {
    int f4 = it * 512 + tid;        // 0..4095, coalesced float4 stream
    int j = f4 >> 4;                // row 0..255
    int c4 = f4 & 15;               // float4 index within row (d = 4*c4)
    float4 kv = K4[f4];
    unsigned lo = pk(kv.x, kv.y), hi = pk(kv.z, kv.w);
    int gs = (c4 >> 1) ^ (j & 7);   // 16B-granule swizzle
    *(uint2*)&Kb[j * 64 + gs * 8 + (c4 & 1) * 4] = make_uint2(lo, hi);

    float4 vv = V4[f4];
    float vals[4] = {vv.x, vv.y, vv.z, vv.w};
    int dc = c4 * 4;
#pragma unroll
    for (int c = 0; c < 4; ++c) {   // transpose store (one-time; minor conflicts)
      int d = dc + c;
      int gv = (j >> 3) ^ (d & 15);
      Vt[d * 256 + gv * 8 + (j & 7)] = (unsigned short)bf16r(vals[c]);
    }
  }
  __syncthreads();

  // ---------------- per-wave attention over 16-row i-chunks ----------------
  const int w = tid >> 6, l = tid & 63, g = l >> 4, il = l & 15;
  const float* Qs = q + qkvOff;
  const float4* Pos4 = (const float4*)(pos + pmOff);
  const float4* Msk4 = (const float4*)(msk + pmOff);
  float* Out = out + qkvOff;
  const f32x4 zero = {0.f, 0.f, 0.f, 0.f};

#pragma unroll 1
  for (int chunk = 0; chunk < 2; ++chunk) {
    const int i0 = (w * 2 + chunk) * 16;
    const int irow = i0 + il;

    // Q B-frags (B[k=d][n=i] = Q[i][d]): 8 consecutive d per lane, 2 k-steps
    const float4* Qr = (const float4*)(Qs + (size_t)irow * 64);
    short8 qf0 = pack8(Qr[2 * g], Qr[2 * g + 1]);
    short8 qf1 = pack8(Qr[8 + 2 * g], Qr[9 + 2 * g]);

    // QK^T: simT[j=16jt+4g+r][i=irow], j streamed over 16 tiles in regs
    float sv[16][4];
#pragma unroll
    for (int jt = 0; jt < 16; ++jt) {
      float4 pf = Pos4[(size_t)irow * 64 + jt * 4 + g];  // pos[i][16jt+4g ..+3]
      float4 mf = Msk4[(size_t)irow * 64 + jt * 4 + g];
      int j16 = jt * 16 + il;
      const short8* kr = (const short8*)&Kb[j16 * 64];
      short8 kf0 = kr[(0 + g) ^ (j16 & 7)];   // K[j16][d=8g..8g+7]
      short8 kf1 = kr[(4 + g) ^ (j16 & 7)];   // K[j16][d=32+8g..]
      f32x4 acc = __builtin_amdgcn_mfma_f32_16x16x32_bf16(kf0, qf0, zero, 0, 0, 0);
      acc = __builtin_amdgcn_mfma_f32_16x16x32_bf16(kf1, qf1, acc, 0, 0, 0);
      sv[jt][0] = (acc[0] * 0.125f + pf.x) * mf.x;
      sv[jt][1] = (acc[1] * 0.125f + pf.y) * mf.y;
      sv[jt][2] = (acc[2] * 0.125f + pf.z) * mf.z;
      sv[jt][3] = (acc[3] * 0.125f + pf.w) * mf.w;
    }

    // ---- softmax over j (in-lane 64 values, then xor16/xor32 across g) ----
    float mx = -3.4e38f;
#pragma unroll
    for (int jt = 0; jt < 16; ++jt)
#pragma unroll
      for (int r = 0; r < 4; ++r) mx = fmaxf(mx, sv[jt][r]);
    mx = fmaxf(mx, __shfl_xor(mx, 16));
    mx = fmaxf(mx, __shfl_xor(mx, 32));
    float sum = 0.f;
#pragma unroll
    for (int jt = 0; jt < 16; ++jt)
#pragma unroll
      for (int r = 0; r < 4; ++r) {
        float e = exp2f((sv[jt][r] - mx) * 1.44269504088896340736f);
        sv[jt][r] = e;
        sum += e;
      }
    sum += __shfl_xor(sum, 16);
    sum += __shfl_xor(sum, 32);
    float rcp = 1.0f / sum;   // deferred normalization

    // pack unnormalized P to bf16 pairs: pd[tile][0]=(r0,r1), [1]=(r2,r3)
    unsigned pd[16][2];
#pragma unroll
    for (int jt = 0; jt < 16; ++jt) {
      pd[jt][0] = pk(sv[jt][0], sv[jt][1]);
      pd[jt][1] = pk(sv[jt][2], sv[jt][3]);
    }

    // ---- PV: transform P C-layout -> A-frag via ds_bpermute, MFMA with Vt ----
    f32x4 ao[4] = {zero, zero, zero, zero};
    const int addrA = (((g & 1) * 2) * 16 + il) * 4;  // source lane * 4
    const int addrB = addrA + 64;                     // +16 lanes
    const bool hi = (g >> 1) != 0;
#pragma unroll
    for (int kt = 0; kt < 8; ++kt) {
      int t0 = 2 * kt, t1 = t0 + 1;
      int a0 = __builtin_amdgcn_ds_bpermute(addrA, (int)pd[t0][0]);
      int b0 = __builtin_amdgcn_ds_bpermute(addrA, (int)pd[t1][0]);
      int a1 = __builtin_amdgcn_ds_bpermute(addrA, (int)pd[t0][1]);
      int b1 = __builtin_amdgcn_ds_bpermute(addrA, (int)pd[t1][1]);
      int a2 = __builtin_amdgcn_ds_bpermute(addrB, (int)pd[t0][0]);
      int b2 = __builtin_amdgcn_ds_bpermute(addrB, (int)pd[t1][0]);
      int a3 = __builtin_amdgcn_ds_bpermute(addrB, (int)pd[t0][1]);
      int b3 = __builtin_amdgcn_ds_bpermute(addrB, (int)pd[t1][1]);
      int4v av;
      av[0] = hi ? b0 : a0;
      av[1] = hi ? b1 : a1;
      av[2] = hi ? b2 : a2;
      av[3] = hi ? b3 : a3;
      short8 af = __builtin_bit_cast(short8, av);   // P[i=il][j=32kt+8g ..+7]
#pragma unroll
      for (int dt = 0; dt < 4; ++dt) {
        int d = dt * 16 + il;
        const short8* vr = (const short8*)&Vt[d * 256];
        short8 vf = vr[(4 * kt + g) ^ il];          // V[j=32kt+8g..][d]
        ao[dt] = __builtin_amdgcn_mfma_f32_16x16x32_bf16(af, vf, ao[dt], 0, 0, 0);
      }
    }

    // ---- epilogue: scale rows by 1/l and store (full-line coalesced) ----
    float rl[4];
#pragma unroll
    for (int r = 0; r < 4; ++r) rl[r] = __shfl(rcp, g * 4 + r);
#pragma unroll
    for (int dt = 0; dt < 4; ++dt)
#pragma unroll
      for (int r = 0; r < 4; ++r)
        Out[(size_t)(i0 + g * 4 + r) * 64 + dt * 16 + il] = ao[dt][r] * rl[r];
  }
}

extern "C" void kernel_launch(void* const* d_in, const int* in_sizes, int n_in,
                              void* d_out, int out_size, void* d_ws, size_t ws_size,
                              hipStream_t stream) {
  const float* q = (const float*)d_in[0];
  const float* k = (const float*)d_in[1];
  const float* v = (const float*)d_in[2];
  const float* pos = (const float*)d_in[3];
  const float* msk = (const float*)d_in[4];
  float* out = (float*)d_out;
  WindowedMaskedAttentionCalculation_72189810311255_kernel<<<1024, 512, 0, stream>>>(
      q, k, v, pos, msk, out);
}

// Round 2
// 799.396 us; speedup vs baseline: 1.2713x; 1.2713x over previous
//
#include <hip/hip_runtime.h>

// Fused windowed masked attention, one workgroup per (b,p,h) slice.
// B=2,P=64,H=8 -> 1024 slices; I=J=256, D=64. fp32 in/out, bf16 MFMA inside.
//
// v3: 512-thread workgroups (8 waves x 2 i-chunks) with __launch_bounds__(512,2).
// v2's (512,4) was honored as 4 blocks/CU -> 64-VGPR cap -> full sv[] spill
// (WRITE_SIZE 233->805 MB). (512,2) = 2 blocks/CU -> 128-VGPR cap, which this
// code fits (v1 used exactly 128). LDS 64 KiB also gives 2 WG/CU -> 16 waves/CU,
// 2x v1's residency, for the latency-bound pos/mask stream.
//
// Layout notes (gfx950 mfma_f32_16x16x32_bf16, all HW-verified mappings):
//   A-frag: A[m=lane&15][k=(lane>>4)*8+jj], jj=0..7
//   B-frag: B[k=(lane>>4)*8+jj][n=lane&15]
//   C/D   : col=lane&15, row=(lane>>4)*4+reg
// We compute simT = K*Q^T (rows=j, cols=i) so softmax-over-j reduces in-lane
// (4 regs x 16 tiles) plus shfl_xor(16),shfl_xor(32).

typedef short short8 __attribute__((ext_vector_type(8)));
typedef float f32x4 __attribute__((ext_vector_type(4)));
typedef int int4v __attribute__((ext_vector_type(4)));

__device__ __forceinline__ unsigned bf16r(float x) {
  unsigned u = __float_as_uint(x);
  return (u + 0x7FFFu + ((u >> 16) & 1u)) >> 16;  // round-to-nearest-even
}
__device__ __forceinline__ unsigned pk(float a, float b) {
  return bf16r(a) | (bf16r(b) << 16);
}
__device__ __forceinline__ short8 pack8(float4 a, float4 b) {
  int4v t;
  t[0] = (int)pk(a.x, a.y); t[1] = (int)pk(a.z, a.w);
  t[2] = (int)pk(b.x, b.y); t[3] = (int)pk(b.z, b.w);
  return __builtin_bit_cast(short8, t);
}

__global__ __launch_bounds__(512, 2)
void WindowedMaskedAttentionCalculation_72189810311255_kernel(
    const float* __restrict__ q, const float* __restrict__ k,
    const float* __restrict__ v, const float* __restrict__ pos,
    const float* __restrict__ msk, float* __restrict__ out) {
  // K bf16 row-major [256][64], 128B rows; 16B granule swizzled by (j&7).
  // Vt bf16 [64][256] (V transposed), 512B rows; granule swizzled by (d&15).
  __shared__ unsigned short Kb[16384];   // 32 KiB
  __shared__ unsigned short Vt[16384];   // 32 KiB  -> 64 KiB total, 2 WG/CU

  const int s = blockIdx.x;
  const int tid = threadIdx.x;
  const size_t qkvOff = (size_t)s * 16384;   // 256*64
  const size_t pmOff = (size_t)s * 65536;    // 256*256

  // ---------------- stage K (swizzled) and V^T (swizzled) ----------------
  const float4* K4 = (const float4*)(k + qkvOff);
  const float4* V4 = (const float4*)(v + qkvOff);
#pragma unroll
  for (int it = 0; it < 8; ++it) {
    int f4 = it * 512 + tid;        // 0..4095, coalesced float4 stream
    int j = f4 >> 4;                // row 0..255
    int c4 = f4 & 15;               // float4 index within row (d = 4*c4)
    float4 kv = K4[f4];
    unsigned lo = pk(kv.x, kv.y), hi = pk(kv.z, kv.w);
    int gs = (c4 >> 1) ^ (j & 7);   // 16B-granule swizzle
    *(uint2*)&Kb[j * 64 + gs * 8 + (c4 & 1) * 4] = make_uint2(lo, hi);

    float4 vv = V4[f4];
    float vals[4] = {vv.x, vv.y, vv.z, vv.w};
    int dc = c4 * 4;
#pragma unroll
    for (int c = 0; c < 4; ++c) {   // transpose store (one-time; minor conflicts)
      int d = dc + c;
      int gv = (j >> 3) ^ (d & 15);
      Vt[d * 256 + gv * 8 + (j & 7)] = (unsigned short)bf16r(vals[c]);
    }
  }
  __syncthreads();

  // ---------------- per-wave attention over 16-row i-chunks ----------------
  const int w = tid >> 6, l = tid & 63, g = l >> 4, il = l & 15;
  const float* Qs = q + qkvOff;
  const float4* Pos4 = (const float4*)(pos + pmOff);
  const float4* Msk4 = (const float4*)(msk + pmOff);
  float* Out = out + qkvOff;
  const f32x4 zero = {0.f, 0.f, 0.f, 0.f};

#pragma unroll 1
  for (int chunk = 0; chunk < 2; ++chunk) {
    const int i0 = (w * 2 + chunk) * 16;
    const int irow = i0 + il;

    // Q B-frags (B[k=d][n=i] = Q[i][d]): 8 consecutive d per lane, 2 k-steps
    const float4* Qr = (const float4*)(Qs + (size_t)irow * 64);
    short8 qf0 = pack8(Qr[2 * g], Qr[2 * g + 1]);
    short8 qf1 = pack8(Qr[8 + 2 * g], Qr[9 + 2 * g]);

    // QK^T: simT[j=16jt+4g+r][i=irow], j streamed over 16 tiles in regs
    float sv[16][4];
#pragma unroll
    for (int jt = 0; jt < 16; ++jt) {
      float4 pf = Pos4[(size_t)irow * 64 + jt * 4 + g];  // pos[i][16jt+4g ..+3]
      float4 mf = Msk4[(size_t)irow * 64 + jt * 4 + g];
      int j16 = jt * 16 + il;
      const short8* kr = (const short8*)&Kb[j16 * 64];
      short8 kf0 = kr[(0 + g) ^ (j16 & 7)];   // K[j16][d=8g..8g+7]
      short8 kf1 = kr[(4 + g) ^ (j16 & 7)];   // K[j16][d=32+8g..]
      f32x4 acc = __builtin_amdgcn_mfma_f32_16x16x32_bf16(kf0, qf0, zero, 0, 0, 0);
      acc = __builtin_amdgcn_mfma_f32_16x16x32_bf16(kf1, qf1, acc, 0, 0, 0);
      sv[jt][0] = (acc[0] * 0.125f + pf.x) * mf.x;
      sv[jt][1] = (acc[1] * 0.125f + pf.y) * mf.y;
      sv[jt][2] = (acc[2] * 0.125f + pf.z) * mf.z;
      sv[jt][3] = (acc[3] * 0.125f + pf.w) * mf.w;
    }

    // ---- softmax over j (in-lane 64 values, then xor16/xor32 across g) ----
    float mx = -3.4e38f;
#pragma unroll
    for (int jt = 0; jt < 16; ++jt)
#pragma unroll
      for (int r = 0; r < 4; ++r) mx = fmaxf(mx, sv[jt][r]);
    mx = fmaxf(mx, __shfl_xor(mx, 16));
    mx = fmaxf(mx, __shfl_xor(mx, 32));
    float sum = 0.f;
#pragma unroll
    for (int jt = 0; jt < 16; ++jt)
#pragma unroll
      for (int r = 0; r < 4; ++r) {
        float e = exp2f((sv[jt][r] - mx) * 1.44269504088896340736f);
        sv[jt][r] = e;
        sum += e;
      }
    sum += __shfl_xor(sum, 16);
    sum += __shfl_xor(sum, 32);
    float rcp = 1.0f / sum;   // deferred normalization

    // pack unnormalized P to bf16 pairs: pd[tile][0]=(r0,r1), [1]=(r2,r3)
    unsigned pd[16][2];
#pragma unroll
    for (int jt = 0; jt < 16; ++jt) {
      pd[jt][0] = pk(sv[jt][0], sv[jt][1]);
      pd[jt][1] = pk(sv[jt][2], sv[jt][3]);
    }

    // ---- PV: transform P C-layout -> A-frag via ds_bpermute, MFMA with Vt ----
    f32x4 ao[4] = {zero, zero, zero, zero};
    const int addrA = (((g & 1) * 2) * 16 + il) * 4;  // source lane * 4
    const int addrB = addrA + 64;                     // +16 lanes
    const bool hi = (g >> 1) != 0;
#pragma unroll
    for (int kt = 0; kt < 8; ++kt) {
      int t0 = 2 * kt, t1 = t0 + 1;
      int a0 = __builtin_amdgcn_ds_bpermute(addrA, (int)pd[t0][0]);
      int b0 = __builtin_amdgcn_ds_bpermute(addrA, (int)pd[t1][0]);
      int a1 = __builtin_amdgcn_ds_bpermute(addrA, (int)pd[t0][1]);
      int b1 = __builtin_amdgcn_ds_bpermute(addrA, (int)pd[t1][1]);
      int a2 = __builtin_amdgcn_ds_bpermute(addrB, (int)pd[t0][0]);
      int b2 = __builtin_amdgcn_ds_bpermute(addrB, (int)pd[t1][0]);
      int a3 = __builtin_amdgcn_ds_bpermute(addrB, (int)pd[t0][1]);
      int b3 = __builtin_amdgcn_ds_bpermute(addrB, (int)pd[t1][1]);
      int4v av;
      av[0] = hi ? b0 : a0;
      av[1] = hi ? b1 : a1;
      av[2] = hi ? b2 : a2;
      av[3] = hi ? b3 : a3;
      short8 af = __builtin_bit_cast(short8, av);   // P[i=il][j=32kt+8g ..+7]
#pragma unroll
      for (int dt = 0; dt < 4; ++dt) {
        int d = dt * 16 + il;
        const short8* vr = (const short8*)&Vt[d * 256];
        short8 vf = vr[(4 * kt + g) ^ il];          // V[j=32kt+8g..][d]
        ao[dt] = __builtin_amdgcn_mfma_f32_16x16x32_bf16(af, vf, ao[dt], 0, 0, 0);
      }
    }

    // ---- epilogue: scale rows by 1/l and store (full-line coalesced) ----
    float rl[4];
#pragma unroll
    for (int r = 0; r < 4; ++r) rl[r] = __shfl(rcp, g * 4 + r);
#pragma unroll
    for (int dt = 0; dt < 4; ++dt)
#pragma unroll
      for (int r = 0; r < 4; ++r)
        Out[(size_t)(i0 + g * 4 + r) * 64 + dt * 16 + il] = ao[dt][r] * rl[r];
  }
}

extern "C" void kernel_launch(void* const* d_in, const int* in_sizes, int n_in,
                              void* d_out, int out_size, void* d_ws, size_t ws_size,
                              hipStream_t stream) {
  const float* q = (const float*)d_in[0];
  const float* k = (const float*)d_in[1];
  const float* v = (const float*)d_in[2];
  const float* pos = (const float*)d_in[3];
  const float* msk = (const float*)d_in[4];
  float* out = (float*)d_out;
  WindowedMaskedAttentionCalculation_72189810311255_kernel<<<1024, 512, 0, stream>>>(
      q, k, v, pos, msk, out);
}

// Round 5
// 712.327 us; speedup vs baseline: 1.4266x; 1.1222x over previous
//
#include <hip/hip_runtime.h>

// Fused windowed masked attention, one workgroup per (b,p,h) slice.
// B=2,P=64,H=8 -> 1024 slices; I=J=256, D=64. fp32 in/out, bf16 MFMA inside.
//
// v4 (2nd resubmit; two container-level infra failures, no verifier verdict):
// ONLINE softmax (flash-style, deferred rescale THR=8). v1/v3's two-pass
// structure kept sv[16][4]+pd[16][2] live (~140 regs) -> spilled ~160-320 MB
// of scratch traffic per dispatch AND could not fit 2x512-thread blocks in the
// 512-reg/SIMD file (v3 occupancy 21%). Fusing QK^T+softmax+PV per 32-j step
// drops live state to ~100 regs: no spill, 2 blocks/CU (16 waves), and an
// explicit depth-2 pos/mask prefetch keeps the HBM stream in flight.
//
// Layout notes (gfx950 mfma_f32_16x16x32_bf16, all HW-verified mappings):
//   A-frag: A[m=lane&15][k=(lane>>4)*8+jj], jj=0..7
//   B-frag: B[k=(lane>>4)*8+jj][n=lane&15]
//   C/D   : col=lane&15, row=(lane>>4)*4+reg
// QK^T computes simT = K*Q^T (rows=j, cols=i): row-softmax reduces in-lane
// (8 vals/step) + shfl_xor(16),shfl_xor(32) across the 4 lanes sharing i=il.

typedef short short8 __attribute__((ext_vector_type(8)));
typedef float f32x4 __attribute__((ext_vector_type(4)));
typedef int int4v __attribute__((ext_vector_type(4)));

__device__ __forceinline__ unsigned bf16r(float x) {
  unsigned u = __float_as_uint(x);
  return (u + 0x7FFFu + ((u >> 16) & 1u)) >> 16;  // round-to-nearest-even
}
__device__ __forceinline__ unsigned pk(float a, float b) {
  return bf16r(a) | (bf16r(b) << 16);
}
__device__ __forceinline__ short8 pack8(float4 a, float4 b) {
  int4v t;
  t[0] = (int)pk(a.x, a.y); t[1] = (int)pk(a.z, a.w);
  t[2] = (int)pk(b.x, b.y); t[3] = (int)pk(b.z, b.w);
  return __builtin_bit_cast(short8, t);
}

#define LOG2E 1.44269504088896340736f

__global__ __launch_bounds__(512, 2)
void WindowedMaskedAttentionCalculation_72189810311255_kernel(
    const float* __restrict__ q, const float* __restrict__ k,
    const float* __restrict__ v, const float* __restrict__ pos,
    const float* __restrict__ msk, float* __restrict__ out) {
  // K bf16 row-major [256][64], 128B rows; 16B granule swizzled by (j&7).
  // Vt bf16 [64][256] (V transposed), 512B rows; granule swizzled by (d&15).
  __shared__ unsigned short Kb[16384];   // 32 KiB
  __shared__ unsigned short Vt[16384];   // 32 KiB  -> 64 KiB total, 2 WG/CU

  const int s = blockIdx.x;
  const int tid = threadIdx.x;
  const size_t qkvOff = (size_t)s * 16384;   // 256*64
  const size_t pmOff = (size_t)s * 65536;    // 256*256

  // ---------------- stage K (swizzled) and V^T (swizzled) ----------------
  const float4* K4 = (const float4*)(k + qkvOff);
  const float4* V4 = (const float4*)(v + qkvOff);
#pragma unroll
  for (int it = 0; it < 8; ++it) {
    int f4 = it * 512 + tid;        // 0..4095, coalesced float4 stream
    int j = f4 >> 4;                // row 0..255
    int c4 = f4 & 15;               // float4 index within row (d = 4*c4)
    float4 kv = K4[f4];
    unsigned lo = pk(kv.x, kv.y), hi = pk(kv.z, kv.w);
    int gs = (c4 >> 1) ^ (j & 7);   // 16B-granule swizzle
    *(uint2*)&Kb[j * 64 + gs * 8 + (c4 & 1) * 4] = make_uint2(lo, hi);

    float4 vv = V4[f4];
    float vals[4] = {vv.x, vv.y, vv.z, vv.w};
    int dc = c4 * 4;
#pragma unroll
    for (int c = 0; c < 4; ++c) {   // transpose store (one-time; minor conflicts)
      int d = dc + c;
      int gv = (j >> 3) ^ (d & 15);
      Vt[d * 256 + gv * 8 + (j & 7)] = (unsigned short)bf16r(vals[c]);
    }
  }
  __syncthreads();

  // ---------------- per-wave attention over 16-row i-chunks ----------------
  const int w = tid >> 6, l = tid & 63, g = l >> 4, il = l & 15;
  const float* Qs = q + qkvOff;
  const float4* Pos4 = (const float4*)(pos + pmOff);
  const float4* Msk4 = (const float4*)(msk + pmOff);
  float* Out = out + qkvOff;
  const f32x4 zero = {0.f, 0.f, 0.f, 0.f};

  // bpermute constants for P C-layout -> A-frag (per 32-j step)
  const int addrA = (((g & 1) * 2) * 16 + il) * 4;  // source lane * 4
  const int addrB = addrA + 64;                     // +16 lanes
  const bool hi = (g >> 1) != 0;

#pragma unroll 1
  for (int chunk = 0; chunk < 2; ++chunk) {
    const int i0 = (w * 2 + chunk) * 16;
    const int irow = i0 + il;

    // Q B-frags (B[k=d][n=i] = Q[i][d]): 8 consecutive d per lane, 2 k-steps
    const float4* Qr = (const float4*)(Qs + (size_t)irow * 64);
    short8 qf0 = pack8(Qr[2 * g], Qr[2 * g + 1]);
    short8 qf1 = pack8(Qr[8 + 2 * g], Qr[9 + 2 * g]);

    // depth-2 software prefetch of pos/mask (2 tiles = 4 float4 per step)
    float4 pfb[2][2], mfb[2][2];
#pragma unroll
    for (int t = 0; t < 2; ++t) {
      pfb[t][0] = Pos4[(size_t)irow * 64 + (2 * t) * 4 + g];
      mfb[t][0] = Msk4[(size_t)irow * 64 + (2 * t) * 4 + g];
      pfb[t][1] = Pos4[(size_t)irow * 64 + (2 * t + 1) * 4 + g];
      mfb[t][1] = Msk4[(size_t)irow * 64 + (2 * t + 1) * 4 + g];
    }

    f32x4 ao[4] = {zero, zero, zero, zero};
    float m = -3.0e38f, lsum = 0.f;

    // ---- fused pass over j: 8 steps x 32 j-values ----
#pragma unroll
    for (int t = 0; t < 8; ++t) {
      float4 pf0 = pfb[t & 1][0], mf0 = mfb[t & 1][0];
      float4 pf1 = pfb[t & 1][1], mf1 = mfb[t & 1][1];
      if (t < 6) {  // prefetch step t+2 into the buffer just freed
        pfb[t & 1][0] = Pos4[(size_t)irow * 64 + (2 * (t + 2)) * 4 + g];
        mfb[t & 1][0] = Msk4[(size_t)irow * 64 + (2 * (t + 2)) * 4 + g];
        pfb[t & 1][1] = Pos4[(size_t)irow * 64 + (2 * (t + 2) + 1) * 4 + g];
        mfb[t & 1][1] = Msk4[(size_t)irow * 64 + (2 * (t + 2) + 1) * 4 + g];
      }

      // QK^T: two 16x16 tiles (j = 32t .. 32t+31)
      int j16a = (2 * t) * 16 + il;
      const short8* kra = (const short8*)&Kb[j16a * 64];
      short8 ka0 = kra[(0 + g) ^ (j16a & 7)];
      short8 ka1 = kra[(4 + g) ^ (j16a & 7)];
      f32x4 acc0 = __builtin_amdgcn_mfma_f32_16x16x32_bf16(ka0, qf0, zero, 0, 0, 0);
      acc0 = __builtin_amdgcn_mfma_f32_16x16x32_bf16(ka1, qf1, acc0, 0, 0, 0);
      int j16b = (2 * t + 1) * 16 + il;
      const short8* krb = (const short8*)&Kb[j16b * 64];
      short8 kb0 = krb[(0 + g) ^ (j16b & 7)];
      short8 kb1 = krb[(4 + g) ^ (j16b & 7)];
      f32x4 acc1 = __builtin_amdgcn_mfma_f32_16x16x32_bf16(kb0, qf0, zero, 0, 0, 0);
      acc1 = __builtin_amdgcn_mfma_f32_16x16x32_bf16(kb1, qf1, acc1, 0, 0, 0);

      float s0[4], s1[4];
      s0[0] = (acc0[0] * 0.125f + pf0.x) * mf0.x;
      s0[1] = (acc0[1] * 0.125f + pf0.y) * mf0.y;
      s0[2] = (acc0[2] * 0.125f + pf0.z) * mf0.z;
      s0[3] = (acc0[3] * 0.125f + pf0.w) * mf0.w;
      s1[0] = (acc1[0] * 0.125f + pf1.x) * mf1.x;
      s1[1] = (acc1[1] * 0.125f + pf1.y) * mf1.y;
      s1[2] = (acc1[2] * 0.125f + pf1.z) * mf1.z;
      s1[3] = (acc1[3] * 0.125f + pf1.w) * mf1.w;

      // per-row (i=il) max of these 32 j's: in-lane 8, then across the 4 g-lanes
      float tmax = fmaxf(fmaxf(fmaxf(s0[0], s0[1]), fmaxf(s0[2], s0[3])),
                         fmaxf(fmaxf(s1[0], s1[1]), fmaxf(s1[2], s1[3])));
      tmax = fmaxf(tmax, __shfl_xor(tmax, 16));
      tmax = fmaxf(tmax, __shfl_xor(tmax, 32));

      // deferred rescale (THR=8 in ln units): wave-uniform decision
      if (__any(tmax > m + 8.0f)) {
        float nm = fmaxf(m, tmax);                  // per-row new max (same across g)
        float sc = exp2f((m - nm) * LOG2E);         // 0 on first trigger (m=-3e38)
        float scr[4];
#pragma unroll
        for (int r = 0; r < 4; ++r) scr[r] = __shfl(sc, g * 4 + r);  // row 4g+r scale
#pragma unroll
        for (int dt = 0; dt < 4; ++dt)
#pragma unroll
          for (int r = 0; r < 4; ++r) ao[dt][r] *= scr[r];
        lsum *= sc;
        m = nm;
      }

      // P = exp(s - m)  (bounded by e^8), accumulate row-sum in-lane
      float p0[4], p1[4];
#pragma unroll
      for (int r = 0; r < 4; ++r) {
        p0[r] = exp2f((s0[r] - m) * LOG2E);
        p1[r] = exp2f((s1[r] - m) * LOG2E);
        lsum += p0[r] + p1[r];
      }
      unsigned pd00 = pk(p0[0], p0[1]), pd01 = pk(p0[2], p0[3]);
      unsigned pd10 = pk(p1[0], p1[1]), pd11 = pk(p1[2], p1[3]);

      // PV for this 32-j block: P C-layout -> A-frag via ds_bpermute, MFMA w/ Vt
      int a0 = __builtin_amdgcn_ds_bpermute(addrA, (int)pd00);
      int b0 = __builtin_amdgcn_ds_bpermute(addrA, (int)pd10);
      int a1 = __builtin_amdgcn_ds_bpermute(addrA, (int)pd01);
      int b1 = __builtin_amdgcn_ds_bpermute(addrA, (int)pd11);
      int a2 = __builtin_amdgcn_ds_bpermute(addrB, (int)pd00);
      int b2 = __builtin_amdgcn_ds_bpermute(addrB, (int)pd10);
      int a3 = __builtin_amdgcn_ds_bpermute(addrB, (int)pd01);
      int b3 = __builtin_amdgcn_ds_bpermute(addrB, (int)pd11);
      int4v av;
      av[0] = hi ? b0 : a0;
      av[1] = hi ? b1 : a1;
      av[2] = hi ? b2 : a2;
      av[3] = hi ? b3 : a3;
      short8 af = __builtin_bit_cast(short8, av);   // P[i=il][j=32t+8g ..+7]
#pragma unroll
      for (int dt = 0; dt < 4; ++dt) {
        int d = dt * 16 + il;
        const short8* vr = (const short8*)&Vt[d * 256];
        short8 vf = vr[(4 * t + g) ^ il];           // V[j=32t+8g..][d]
        ao[dt] = __builtin_amdgcn_mfma_f32_16x16x32_bf16(af, vf, ao[dt], 0, 0, 0);
      }
    }

    // ---- finish: row-sum across g-lanes, normalize, store ----
    lsum += __shfl_xor(lsum, 16);
    lsum += __shfl_xor(lsum, 32);
    float rcp = 1.0f / lsum;
    float rl[4];
#pragma unroll
    for (int r = 0; r < 4; ++r) rl[r] = __shfl(rcp, g * 4 + r);
#pragma unroll
    for (int dt = 0; dt < 4; ++dt)
#pragma unroll
      for (int r = 0; r < 4; ++r)
        Out[(size_t)(i0 + g * 4 + r) * 64 + dt * 16 + il] = ao[dt][r] * rl[r];
  }
}

extern "C" void kernel_launch(void* const* d_in, const int* in_sizes, int n_in,
                              void* d_out, int out_size, void* d_ws, size_t ws_size,
                              hipStream_t stream) {
  const float* q = (const float*)d_in[0];
  const float* k = (const float*)d_in[1];
  const float* v = (const float*)d_in[2];
  const float* pos = (const float*)d_in[3];
  const float* msk = (const float*)d_in[4];
  float* out = (float*)d_out;
  WindowedMaskedAttentionCalculation_72189810311255_kernel<<<1024, 512, 0, stream>>>(
      q, k, v, pos, msk, out);
}